// Round 7
// baseline (497.979 us; speedup 1.0000x reference)
//
#include <hip/hip_runtime.h>
#include <hip/hip_bf16.h>

#define NEG_SLOPE 0.2f
#define LRELU(v) ((v) > 0.f ? (v) : NEG_SLOPE * (v))
#define BBITS 7
#define BSZ 128  // nodes per bucket

typedef unsigned short ushort_t;
typedef unsigned int uint_t;

static inline int cdiv(int a, int b) { return (a + b - 1) / b; }

__device__ __forceinline__ float wsum(float v) {
#pragma unroll
    for (int o = 32; o; o >>= 1) v += __shfl_xor(v, o);
    return v;
}
__device__ __forceinline__ ushort_t f2bfbits(float f) {
    __hip_bfloat16 b = __float2bfloat16(f);
    return *reinterpret_cast<ushort_t*>(&b);
}

// =================== bucket-sort CSR build ===================
__global__ __launch_bounds__(256) void k_zero_int(int* p, int n) {
    int i = blockIdx.x * 256 + threadIdx.x;
    if (i < n) p[i] = 0;
}

__global__ __launch_bounds__(256) void k_bhist(const int* __restrict__ ei, int E, int ET, int NB,
                                               int* __restrict__ bcnt) {
    extern __shared__ int hist[];
    for (int i = threadIdx.x; i < NB; i += 256) hist[i] = 0;
    __syncthreads();
    int stride = gridDim.x * 256;
    for (int i = blockIdx.x * 256 + threadIdx.x; i < ET; i += stride) {
        int d = (i < E) ? ei[E + i] : (i - E);  // self loops appended
        atomicAdd(&hist[d >> BBITS], 1);
    }
    __syncthreads();
    for (int i = threadIdx.x; i < NB; i += 256) {
        int c = hist[i];
        if (c) atomicAdd(&bcnt[i], c);
    }
}

__global__ void k_scan_small(const int* __restrict__ bcnt, int NB,
                             int* __restrict__ boff, int* __restrict__ bcur,
                             int* __restrict__ offs, int N, int ET) {
    extern __shared__ int sm[];
    for (int i = threadIdx.x; i < NB; i += blockDim.x) sm[i] = bcnt[i];
    __syncthreads();
    if (threadIdx.x == 0) {
        int run = 0;
        for (int i = 0; i < NB; i++) { int c = sm[i]; sm[i] = run; run += c; }
    }
    __syncthreads();
    for (int i = threadIdx.x; i < NB; i += blockDim.x) { boff[i] = sm[i]; bcur[i] = sm[i]; }
    if (threadIdx.x == 0) { boff[NB] = ET; offs[N] = ET; }
}

__global__ __launch_bounds__(256) void k_bscatter(const int* __restrict__ ei, int E, int ET, int NB,
                                                  int* __restrict__ bcur,
                                                  long long* __restrict__ tmp) {
    extern __shared__ int sm2[];
    int* hist = sm2;
    int* cur = sm2 + NB;
    const int CH = 4096;
    int c0 = blockIdx.x * CH;
    int c1 = min(ET, c0 + CH);
    for (int i = threadIdx.x; i < NB; i += 256) hist[i] = 0;
    __syncthreads();
    for (int i = c0 + threadIdx.x; i < c1; i += 256) {
        int d = (i < E) ? ei[E + i] : (i - E);
        atomicAdd(&hist[d >> BBITS], 1);
    }
    __syncthreads();
    for (int i = threadIdx.x; i < NB; i += 256) {
        int c = hist[i];
        cur[i] = c ? atomicAdd(&bcur[i], c) : 0;
    }
    __syncthreads();
    for (int i = c0 + threadIdx.x; i < c1; i += 256) {
        int s = (i < E) ? ei[i] : (i - E);
        int d = (i < E) ? ei[E + i] : (i - E);
        int pos = atomicAdd(&cur[d >> BBITS], 1);
        tmp[pos] = ((long long)d << 32) | (unsigned)s;
    }
}

__global__ __launch_bounds__(256) void k_csrfin(const long long* __restrict__ tmp,
                                                const int* __restrict__ boff, int NB, int N,
                                                int* __restrict__ offs, int* __restrict__ ssrc) {
    __shared__ int deg[BSZ], cur[BSZ], sc[BSZ];
    int b = blockIdx.x;
    int node0 = b << BBITS;
    int nn = min(BSZ, N - node0);
    int r0 = boff[b], r1 = boff[b + 1];
    int t = threadIdx.x;
    if (t < BSZ) deg[t] = 0;
    __syncthreads();
    for (int i = r0 + t; i < r1; i += 256) {
        int d = (int)(tmp[i] >> 32);
        atomicAdd(&deg[d - node0], 1);
    }
    __syncthreads();
    if (t < BSZ) sc[t] = deg[t];
    __syncthreads();
    for (int o = 1; o < BSZ; o <<= 1) {
        int v = 0;
        if (t < BSZ && t >= o) v = sc[t - o];
        __syncthreads();
        if (t < BSZ) sc[t] += v;
        __syncthreads();
    }
    if (t < BSZ) {
        int ex = sc[t] - deg[t];
        cur[t] = r0 + ex;
        if (t < nn) offs[node0 + t] = r0 + ex;
    }
    __syncthreads();
    for (int i = r0 + t; i < r1; i += 256) {
        long long v = tmp[i];
        int d = (int)(v >> 32);
        int s = (int)(v & 0xffffffffLL);
        int pos = atomicAdd(&cur[d - node0], 1);
        ssrc[pos] = s;
    }
}

// =================== GEMM: h[N,M] = x[N,128] @ W[128,M], h stored bf16 ===================
template <int M, int TR>
__global__ __launch_bounds__(256) void k_gemm(const float* __restrict__ x,
                                              const float* __restrict__ W,
                                              ushort_t* __restrict__ h, int N) {
    __shared__ float xs[128 * TR];  // xs[k][r], full K staged once
    __shared__ float ws[64 * M];    // ws[k][j], one 64-row half of W at a time
    int t = threadIdx.x;
    int row0 = blockIdx.x * TR;

    {   // load x tile transposed
        int r = t % TR;
        int kv0 = t / TR;
        const int GK = 256 / TR;
        int row = row0 + r;
        for (int kv = kv0; kv < 32; kv += GK) {
            float4 v = make_float4(0.f, 0.f, 0.f, 0.f);
            if (row < N) v = *(const float4*)(x + (size_t)row * 128 + kv * 4);
            xs[(kv * 4 + 0) * TR + r] = v.x;
            xs[(kv * 4 + 1) * TR + r] = v.y;
            xs[(kv * 4 + 2) * TR + r] = v.z;
            xs[(kv * 4 + 3) * TR + r] = v.w;
        }
    }

    constexpr int CQ = M / 4;
    int tx = t % CQ, ty = t / CQ;
    int j0 = tx * 4, r0 = ty * 4;
    float acc[4][4];
#pragma unroll
    for (int a = 0; a < 4; a++)
#pragma unroll
        for (int b = 0; b < 4; b++) acc[a][b] = 0.f;

    for (int ks = 0; ks < 128; ks += 64) {
        __syncthreads();
        const float4* wg = (const float4*)(W + (size_t)ks * M);
        float4* wl = (float4*)ws;
        for (int i = t; i < 64 * M / 4; i += 256) wl[i] = wg[i];
        __syncthreads();
#pragma unroll 8
        for (int k = 0; k < 64; k++) {
            float4 xv = *(const float4*)(xs + (ks + k) * TR + r0);
            float4 wv = *(const float4*)(ws + k * M + j0);
            float xr[4] = {xv.x, xv.y, xv.z, xv.w};
            float wr[4] = {wv.x, wv.y, wv.z, wv.w};
#pragma unroll
            for (int a = 0; a < 4; a++)
#pragma unroll
                for (int b = 0; b < 4; b++) acc[a][b] += xr[a] * wr[b];
        }
    }
#pragma unroll
    for (int a = 0; a < 4; a++) {
        int row = row0 + r0 + a;
        if (row < N) {
            ushort4 pk;
            pk.x = f2bfbits(acc[a][0]);
            pk.y = f2bfbits(acc[a][1]);
            pk.z = f2bfbits(acc[a][2]);
            pk.w = f2bfbits(acc[a][3]);
            *(ushort4*)(h + (size_t)row * M + j0) = pk;
        }
    }
}

// =================== per-node attention projections (bf16 h in, fp32 out) ==========
template <int H>
__global__ __launch_bounds__(256) void k_alpha(const ushort_t* __restrict__ h,
                                               const float* __restrict__ a_src,
                                               const float* __restrict__ a_dst,
                                               float* __restrict__ as, float* __restrict__ ad,
                                               int N) {
    int wid = (blockIdx.x * 256 + threadIdx.x) >> 6;
    int lane = threadIdx.x & 63;
    if (wid >= N * H) return;
    int n = wid / H, hh = wid % H;
    float v = __uint_as_float(((uint_t)h[(size_t)n * (H * 64) + hh * 64 + lane]) << 16);
    float s = v * a_src[hh * 64 + lane];
    float d = v * a_dst[hh * 64 + lane];
#pragma unroll
    for (int off = 32; off; off >>= 1) { s += __shfl_down(s, off); d += __shfl_down(d, off); }
    if (lane == 0) { as[wid] = s; ad[wid] = d; }
}

// ===== gather helper: NBATCH edge-groups, 1 ds_read of {so,p} + 1 global uint4 per group =====
template <int H, int NBATCH, bool PRED>
__device__ __forceinline__ void agg_groups(int b0, int ne, int sub, int cpo, int hself,
                                           const void* metab, const char* hb, float* acc) {
    constexpr int G = 8 * H, EPW = 64 / G;
    uint4 hv[NBATCH];
    float pv[NBATCH];
#pragma unroll
    for (int g = 0; g < NBATCH; g++) {
        int eidx = (b0 + g) * EPW + sub;
        bool ok = !PRED || (eidx < ne);
        unsigned so;
        float p;
        if (H == 2) {
            uint4 m = ((const uint4*)metab)[eidx & 63];
            so = m.x;
            p = hself ? __uint_as_float(m.z) : __uint_as_float(m.y);
        } else {
            uint2 m = ((const uint2*)metab)[eidx & 63];
            so = m.x;
            p = __uint_as_float(m.y);
        }
        pv[g] = ok ? p : 0.f;
        hv[g] = make_uint4(0u, 0u, 0u, 0u);
        if (ok) hv[g] = *(const uint4*)(hb + (so + cpo));
    }
#pragma unroll
    for (int g = 0; g < NBATCH; g++) {
        acc[0] += pv[g] * __uint_as_float(hv[g].x << 16);
        acc[1] += pv[g] * __uint_as_float(hv[g].x & 0xffff0000u);
        acc[2] += pv[g] * __uint_as_float(hv[g].y << 16);
        acc[3] += pv[g] * __uint_as_float(hv[g].y & 0xffff0000u);
        acc[4] += pv[g] * __uint_as_float(hv[g].z << 16);
        acc[5] += pv[g] * __uint_as_float(hv[g].z & 0xffff0000u);
        acc[6] += pv[g] * __uint_as_float(hv[g].w << 16);
        acc[7] += pv[g] * __uint_as_float(hv[g].w & 0xffff0000u);
    }
}

// ======= fused softmax + aggregation: one wave per dst node, bf16 rows, no-max exp =======
template <int H, bool ELU_ACT>
__global__ __launch_bounds__(256) void k_agg_fused(const int* __restrict__ offs,
                                                   const int* __restrict__ ssrc,
                                                   const ushort_t* __restrict__ h,
                                                   const float* __restrict__ as,
                                                   const float* __restrict__ ad,
                                                   const float* __restrict__ bias,
                                                   float* __restrict__ z, int N) {
    constexpr int G = 8 * H;      // lanes per source row (16 B each)
    constexpr int EPW = 64 / G;   // edges per wave-wide load
    constexpr int RB = H * 128;   // row bytes (bf16)
    __shared__ uint4 metab[4][64];
    int w = threadIdx.x >> 6;
    int lane = threadIdx.x & 63;
    int d = blockIdx.x * 4 + w;
    if (d >= N) return;
    void* mb = (void*)metab[w];
    int cpo = (lane % G) * 16;
    int sub = lane / G;
    int hself = (H == 2) ? ((lane % G) >> 3) : 0;
    const char* hb = (const char*)h;

    float adh[H], den[H];
#pragma unroll
    for (int hh = 0; hh < H; hh++) { adh[hh] = ad[(size_t)d * H + hh]; den[hh] = 0.f; }
    float acc[8];
#pragma unroll
    for (int i = 0; i < 8; i++) acc[i] = 0.f;

    int e0 = offs[d], e1 = offs[d + 1];
    for (int cb = e0; cb < e1; cb += 64) {
        int ne = min(64, e1 - cb);
        float p[H];
#pragma unroll
        for (int hh = 0; hh < H; hh++) p[hh] = 0.f;
        unsigned so = 0;
        if (lane < ne) {
            int s_l = ssrc[cb + lane];
            so = (unsigned)s_l * RB;
            if (H == 2) {
                float2 av = ((const float2*)as)[s_l];
                p[0] = __expf(LRELU(av.x + adh[0]));
                p[1] = __expf(LRELU(av.y + adh[1]));
            } else {
                p[0] = __expf(LRELU(as[s_l] + adh[0]));
            }
        }
#pragma unroll
        for (int hh = 0; hh < H; hh++) den[hh] += wsum(p[hh]);
        if (H == 2) {
            ((uint4*)mb)[lane] =
                make_uint4(so, __float_as_uint(p[0]), __float_as_uint(p[1]), 0u);
        } else {
            ((uint2*)mb)[lane] = make_uint2(so, __float_as_uint(p[0]));
        }
        // gather: unpredicated 4-batches, then 2, then 1, then one predicated partial
        int ngf = ne / EPW;  // complete groups
        int b = 0;
        while (b + 4 <= ngf) { agg_groups<H, 4, false>(b, ne, sub, cpo, hself, mb, hb, acc); b += 4; }
        if (b + 2 <= ngf)    { agg_groups<H, 2, false>(b, ne, sub, cpo, hself, mb, hb, acc); b += 2; }
        if (b < ngf)         { agg_groups<H, 1, false>(b, ne, sub, cpo, hself, mb, hb, acc); b += 1; }
        if (ngf * EPW < ne)  { agg_groups<H, 1, true>(ngf, ne, sub, cpo, hself, mb, hb, acc); }
    }
    // fold sub-wave partials: lanes sharing cpo sum across sub
#pragma unroll
    for (int o = G; o < 64; o <<= 1)
#pragma unroll
        for (int i = 0; i < 8; i++) acc[i] += __shfl_xor(acc[i], o);
    if (lane < G) {
        float inv = 1.f / ((H == 2 && hself) ? den[1] : den[0]);
        int c0 = (cpo / 16) * 8;
        float vout[8];
#pragma unroll
        for (int i = 0; i < 8; i++) {
            vout[i] = acc[i] * inv + bias[c0 + i];
            if (ELU_ACT) vout[i] = vout[i] > 0.f ? vout[i] : expm1f(vout[i]);
        }
        float* zp = z + (size_t)d * (H * 64) + c0;
        *(float4*)zp = make_float4(vout[0], vout[1], vout[2], vout[3]);
        *(float4*)(zp + 4) = make_float4(vout[4], vout[5], vout[6], vout[7]);
    }
}

// =================== decode: dot of endpoint embeddings ===================
__global__ __launch_bounds__(256) void k_decode(const int* __restrict__ eli,
                                                const float* __restrict__ z,
                                                float* __restrict__ out, int EL) {
    int wid = (blockIdx.x * 256 + threadIdx.x) >> 6;
    int lane = threadIdx.x & 63;
    if (wid >= EL) return;
    int a = eli[wid], b = eli[EL + wid];
    float p = z[(size_t)a * 64 + lane] * z[(size_t)b * 64 + lane];
#pragma unroll
    for (int off = 32; off; off >>= 1) p += __shfl_down(p, off);
    if (lane == 0) out[wid] = p;
}

extern "C" void kernel_launch(void* const* d_in, const int* in_sizes, int n_in,
                              void* d_out, int out_size, void* d_ws, size_t ws_size,
                              hipStream_t stream) {
    const float* x   = (const float*)d_in[0];
    const int*   ei  = (const int*)d_in[1];
    const int*   eli = (const int*)d_in[2];
    const float* W1  = (const float*)d_in[3];
    const float* as1 = (const float*)d_in[4];
    const float* ad1 = (const float*)d_in[5];
    const float* b1  = (const float*)d_in[6];
    const float* W2  = (const float*)d_in[7];
    const float* as2 = (const float*)d_in[8];
    const float* ad2 = (const float*)d_in[9];
    const float* b2  = (const float*)d_in[10];

    int N  = in_sizes[0] / 128;
    int E  = in_sizes[1] / 2;
    int EL = in_sizes[2] / 2;
    int ET = E + N;
    int NB = cdiv(N, BSZ);

    char* ws = (char*)d_ws;
    size_t off = 0;
    auto alloc = [&](size_t nbytes) -> void* {
        void* p = ws + off;
        off += (nbytes + 255) & ~(size_t)255;
        return p;
    };
    ushort_t* Hbuf = (ushort_t*)alloc((size_t)N * 128 * 2);  // h1 then h2 (bf16)
    float*    Zbuf = (float*)alloc((size_t)N * 128 * 4);     // z1 then z2 (TMP aliases this)
    float*    AS   = (float*)alloc((size_t)N * 2 * 4);
    float*    AD   = (float*)alloc((size_t)N * 2 * 4);
    int*      OFF  = (int*)alloc((size_t)(N + 1) * 4);
    int*      SSRC = (int*)alloc((size_t)ET * 4);
    int*      BCNT = (int*)alloc((size_t)NB * 4);
    int*      BOFF = (int*)alloc((size_t)(NB + 1) * 4);
    int*      BCUR = (int*)alloc((size_t)NB * 4);
    long long* TMP = (long long*)Zbuf;  // (d,s) pairs; Zbuf unused until k_agg L1

    // ---- CSR build via bucket sort (shared by both layers) ----
    k_zero_int<<<cdiv(NB, 256), 256, 0, stream>>>(BCNT, NB);
    k_bhist<<<256, 256, NB * 4, stream>>>(ei, E, ET, NB, BCNT);
    k_scan_small<<<1, 256, NB * 4, stream>>>(BCNT, NB, BOFF, BCUR, OFF, N, ET);
    k_bscatter<<<cdiv(ET, 4096), 256, 2 * NB * 4, stream>>>(ei, E, ET, NB, BCUR, TMP);
    k_csrfin<<<NB, 256, 0, stream>>>(TMP, BOFF, NB, N, OFF, SSRC);

    // ---- layer 1: heads=2, C=64, ELU ----
    k_gemm<128, 32><<<cdiv(N, 32), 256, 0, stream>>>(x, W1, Hbuf, N);
    k_alpha<2><<<cdiv(N * 2, 4), 256, 0, stream>>>(Hbuf, as1, ad1, AS, AD, N);
    k_agg_fused<2, true><<<cdiv(N, 4), 256, 0, stream>>>(OFF, SSRC, Hbuf, AS, AD, b1, Zbuf, N);

    // ---- layer 2: heads=1, C=64, no activation ----
    k_gemm<64, 64><<<cdiv(N, 64), 256, 0, stream>>>(Zbuf, W2, Hbuf, N);
    k_alpha<1><<<cdiv(N, 4), 256, 0, stream>>>(Hbuf, as2, ad2, AS, AD, N);
    k_agg_fused<1, false><<<cdiv(N, 4), 256, 0, stream>>>(OFF, SSRC, Hbuf, AS, AD, b2, Zbuf, N);

    // ---- decode ----
    k_decode<<<cdiv(EL, 4), 256, 0, stream>>>(eli, Zbuf, (float*)d_out, EL);
}

// Round 8
// 497.859 us; speedup vs baseline: 1.0002x; 1.0002x over previous
//
#include <hip/hip_runtime.h>
#include <hip/hip_bf16.h>

#define NEG_SLOPE 0.2f
#define LRELU(v) ((v) > 0.f ? (v) : NEG_SLOPE * (v))
#define BBITS 7
#define BSZ 128  // nodes per bucket

typedef unsigned short ushort_t;
typedef unsigned int uint_t;

static inline int cdiv(int a, int b) { return (a + b - 1) / b; }

__device__ __forceinline__ float wsum(float v) {
#pragma unroll
    for (int o = 32; o; o >>= 1) v += __shfl_xor(v, o);
    return v;
}
__device__ __forceinline__ ushort_t f2bfbits(float f) {
    __hip_bfloat16 b = __float2bfloat16(f);
    return *reinterpret_cast<ushort_t*>(&b);
}

// =================== bucket-sort CSR build ===================
__global__ __launch_bounds__(256) void k_zero_int(int* p, int n) {
    int i = blockIdx.x * 256 + threadIdx.x;
    if (i < n) p[i] = 0;
}

__global__ __launch_bounds__(256) void k_bhist(const int* __restrict__ ei, int E, int ET, int NB,
                                               int* __restrict__ bcnt) {
    extern __shared__ int hist[];
    for (int i = threadIdx.x; i < NB; i += 256) hist[i] = 0;
    __syncthreads();
    int stride = gridDim.x * 256;
    for (int i = blockIdx.x * 256 + threadIdx.x; i < ET; i += stride) {
        int d = (i < E) ? ei[E + i] : (i - E);  // self loops appended
        atomicAdd(&hist[d >> BBITS], 1);
    }
    __syncthreads();
    for (int i = threadIdx.x; i < NB; i += 256) {
        int c = hist[i];
        if (c) atomicAdd(&bcnt[i], c);
    }
}

__global__ void k_scan_small(const int* __restrict__ bcnt, int NB,
                             int* __restrict__ boff, int* __restrict__ bcur,
                             int* __restrict__ offs, int N, int ET) {
    extern __shared__ int sm[];
    for (int i = threadIdx.x; i < NB; i += blockDim.x) sm[i] = bcnt[i];
    __syncthreads();
    if (threadIdx.x == 0) {
        int run = 0;
        for (int i = 0; i < NB; i++) { int c = sm[i]; sm[i] = run; run += c; }
    }
    __syncthreads();
    for (int i = threadIdx.x; i < NB; i += blockDim.x) { boff[i] = sm[i]; bcur[i] = sm[i]; }
    if (threadIdx.x == 0) { boff[NB] = ET; offs[N] = ET; }
}

__global__ __launch_bounds__(256) void k_bscatter(const int* __restrict__ ei, int E, int ET, int NB,
                                                  int* __restrict__ bcur,
                                                  long long* __restrict__ tmp) {
    extern __shared__ int sm2[];
    int* hist = sm2;
    int* cur = sm2 + NB;
    const int CH = 4096;
    int c0 = blockIdx.x * CH;
    int c1 = min(ET, c0 + CH);
    for (int i = threadIdx.x; i < NB; i += 256) hist[i] = 0;
    __syncthreads();
    for (int i = c0 + threadIdx.x; i < c1; i += 256) {
        int d = (i < E) ? ei[E + i] : (i - E);
        atomicAdd(&hist[d >> BBITS], 1);
    }
    __syncthreads();
    for (int i = threadIdx.x; i < NB; i += 256) {
        int c = hist[i];
        cur[i] = c ? atomicAdd(&bcur[i], c) : 0;
    }
    __syncthreads();
    for (int i = c0 + threadIdx.x; i < c1; i += 256) {
        int s = (i < E) ? ei[i] : (i - E);
        int d = (i < E) ? ei[E + i] : (i - E);
        int pos = atomicAdd(&cur[d >> BBITS], 1);
        tmp[pos] = ((long long)d << 32) | (unsigned)s;
    }
}

__global__ __launch_bounds__(256) void k_csrfin(const long long* __restrict__ tmp,
                                                const int* __restrict__ boff, int NB, int N,
                                                int* __restrict__ offs, int* __restrict__ ssrc) {
    __shared__ int deg[BSZ], cur[BSZ], sc[BSZ];
    int b = blockIdx.x;
    int node0 = b << BBITS;
    int nn = min(BSZ, N - node0);
    int r0 = boff[b], r1 = boff[b + 1];
    int t = threadIdx.x;
    if (t < BSZ) deg[t] = 0;
    __syncthreads();
    for (int i = r0 + t; i < r1; i += 256) {
        int d = (int)(tmp[i] >> 32);
        atomicAdd(&deg[d - node0], 1);
    }
    __syncthreads();
    if (t < BSZ) sc[t] = deg[t];
    __syncthreads();
    for (int o = 1; o < BSZ; o <<= 1) {
        int v = 0;
        if (t < BSZ && t >= o) v = sc[t - o];
        __syncthreads();
        if (t < BSZ) sc[t] += v;
        __syncthreads();
    }
    if (t < BSZ) {
        int ex = sc[t] - deg[t];
        cur[t] = r0 + ex;
        if (t < nn) offs[node0 + t] = r0 + ex;
    }
    __syncthreads();
    for (int i = r0 + t; i < r1; i += 256) {
        long long v = tmp[i];
        int d = (int)(v >> 32);
        int s = (int)(v & 0xffffffffLL);
        int pos = atomicAdd(&cur[d - node0], 1);
        ssrc[pos] = s;
    }
}

// =================== GEMM: h[N,M] = x[N,128] @ W[128,M], h stored bf16 ===================
template <int M, int TR>
__global__ __launch_bounds__(256) void k_gemm(const float* __restrict__ x,
                                              const float* __restrict__ W,
                                              ushort_t* __restrict__ h, int N) {
    __shared__ float xs[128 * TR];  // xs[k][r], full K staged once
    __shared__ float ws[64 * M];    // ws[k][j], one 64-row half of W at a time
    int t = threadIdx.x;
    int row0 = blockIdx.x * TR;

    {   // load x tile transposed
        int r = t % TR;
        int kv0 = t / TR;
        const int GK = 256 / TR;
        int row = row0 + r;
        for (int kv = kv0; kv < 32; kv += GK) {
            float4 v = make_float4(0.f, 0.f, 0.f, 0.f);
            if (row < N) v = *(const float4*)(x + (size_t)row * 128 + kv * 4);
            xs[(kv * 4 + 0) * TR + r] = v.x;
            xs[(kv * 4 + 1) * TR + r] = v.y;
            xs[(kv * 4 + 2) * TR + r] = v.z;
            xs[(kv * 4 + 3) * TR + r] = v.w;
        }
    }

    constexpr int CQ = M / 4;
    int tx = t % CQ, ty = t / CQ;
    int j0 = tx * 4, r0 = ty * 4;
    float acc[4][4];
#pragma unroll
    for (int a = 0; a < 4; a++)
#pragma unroll
        for (int b = 0; b < 4; b++) acc[a][b] = 0.f;

    for (int ks = 0; ks < 128; ks += 64) {
        __syncthreads();
        const float4* wg = (const float4*)(W + (size_t)ks * M);
        float4* wl = (float4*)ws;
        for (int i = t; i < 64 * M / 4; i += 256) wl[i] = wg[i];
        __syncthreads();
#pragma unroll 8
        for (int k = 0; k < 64; k++) {
            float4 xv = *(const float4*)(xs + (ks + k) * TR + r0);
            float4 wv = *(const float4*)(ws + k * M + j0);
            float xr[4] = {xv.x, xv.y, xv.z, xv.w};
            float wr[4] = {wv.x, wv.y, wv.z, wv.w};
#pragma unroll
            for (int a = 0; a < 4; a++)
#pragma unroll
                for (int b = 0; b < 4; b++) acc[a][b] += xr[a] * wr[b];
        }
    }
#pragma unroll
    for (int a = 0; a < 4; a++) {
        int row = row0 + r0 + a;
        if (row < N) {
            ushort4 pk;
            pk.x = f2bfbits(acc[a][0]);
            pk.y = f2bfbits(acc[a][1]);
            pk.z = f2bfbits(acc[a][2]);
            pk.w = f2bfbits(acc[a][3]);
            *(ushort4*)(h + (size_t)row * M + j0) = pk;
        }
    }
}

// =================== per-node attention projections (bf16 h in, fp32 out) ==========
template <int H>
__global__ __launch_bounds__(256) void k_alpha(const ushort_t* __restrict__ h,
                                               const float* __restrict__ a_src,
                                               const float* __restrict__ a_dst,
                                               float* __restrict__ as, float* __restrict__ ad,
                                               int N) {
    int wid = (blockIdx.x * 256 + threadIdx.x) >> 6;
    int lane = threadIdx.x & 63;
    if (wid >= N * H) return;
    int n = wid / H, hh = wid % H;
    float v = __uint_as_float(((uint_t)h[(size_t)n * (H * 64) + hh * 64 + lane]) << 16);
    float s = v * a_src[hh * 64 + lane];
    float d = v * a_dst[hh * 64 + lane];
#pragma unroll
    for (int off = 32; off; off >>= 1) { s += __shfl_down(s, off); d += __shfl_down(d, off); }
    if (lane == 0) { as[wid] = s; ad[wid] = d; }
}

// ===== gather batch: NB_ groups; so broadcast via shfl (32-bit, pre-scaled), p from LDS.
// PRED=false: all slots guaranteed valid (no masks at all).
// PRED=true: loads clamp to a valid edge; only p is zeroed for pad slots.
template <int H, int NB_, bool PRED>
__device__ __forceinline__ void gather_batch(int g0, int ne, int sub, int cpo, int hsel,
                                             unsigned so_reg, const float* pw,
                                             const char* hb, float* acc) {
    constexpr int G = 8 * H, EPW = 64 / G;
    uint4 hv[NB_];
    float pv[NB_];
#pragma unroll
    for (int g = 0; g < NB_; g++) {
        int slot = (g0 + g) * EPW + sub;
        int el = PRED ? min(slot, ne - 1) : slot;
        unsigned so = (unsigned)__shfl((int)so_reg, el);
        hv[g] = *(const uint4*)(hb + (so + cpo));
        float p = pw[el * H + hsel];
        pv[g] = (!PRED || slot < ne) ? p : 0.f;
    }
#pragma unroll
    for (int g = 0; g < NB_; g++) {
        acc[0] += pv[g] * __uint_as_float(hv[g].x << 16);
        acc[1] += pv[g] * __uint_as_float(hv[g].x & 0xffff0000u);
        acc[2] += pv[g] * __uint_as_float(hv[g].y << 16);
        acc[3] += pv[g] * __uint_as_float(hv[g].y & 0xffff0000u);
        acc[4] += pv[g] * __uint_as_float(hv[g].z << 16);
        acc[5] += pv[g] * __uint_as_float(hv[g].z & 0xffff0000u);
        acc[6] += pv[g] * __uint_as_float(hv[g].w << 16);
        acc[7] += pv[g] * __uint_as_float(hv[g].w & 0xffff0000u);
    }
}

// ======= fused softmax + aggregation: one wave per dst node, bf16 rows, no-max exp =======
template <int H, bool ELU_ACT>
__global__ __launch_bounds__(256) void k_agg_fused(const int* __restrict__ offs,
                                                   const int* __restrict__ ssrc,
                                                   const ushort_t* __restrict__ h,
                                                   const float* __restrict__ as,
                                                   const float* __restrict__ ad,
                                                   const float* __restrict__ bias,
                                                   float* __restrict__ z, int N) {
    constexpr int G = 8 * H;      // lanes per source row (16 B each)
    constexpr int EPW = 64 / G;   // edges per wave-wide load group
    constexpr int RB = H * 128;   // row bytes (bf16)
    __shared__ float pl[4][64 * H];
    int w = threadIdx.x >> 6;
    int lane = threadIdx.x & 63;
    int d = blockIdx.x * 4 + w;
    if (d >= N) return;
    float* pw = pl[w];
    int cpo = (lane % G) * 16;
    int sub = lane / G;
    int hsel = (H == 2) ? ((lane % G) >> 3) : 0;
    const char* hb = (const char*)h;

    float adh[H], den[H];
#pragma unroll
    for (int hh = 0; hh < H; hh++) { adh[hh] = ad[(size_t)d * H + hh]; den[hh] = 0.f; }
    float acc[8];
#pragma unroll
    for (int i = 0; i < 8; i++) acc[i] = 0.f;

    int e0 = offs[d], e1 = offs[d + 1];
    for (int cb = e0; cb < e1; cb += 64) {
        int ne = min(64, e1 - cb);
        float p[H];
#pragma unroll
        for (int hh = 0; hh < H; hh++) p[hh] = 0.f;
        unsigned so = 0;
        if (lane < ne) {
            int s_l = ssrc[cb + lane];
            so = (unsigned)s_l * RB;  // pre-scaled byte offset (32-bit)
            if (H == 2) {
                float2 av = ((const float2*)as)[s_l];
                p[0] = __expf(LRELU(av.x + adh[0]));
                p[1] = __expf(LRELU(av.y + adh[1]));
            } else {
                p[0] = __expf(LRELU(as[s_l] + adh[0]));
            }
        }
#pragma unroll
        for (int hh = 0; hh < H; hh++) den[hh] += wsum(p[hh]);
        if (H == 2) {
            pw[lane * 2] = p[0];
            pw[lane * 2 + 1] = p[1];
        } else {
            pw[lane] = p[0];
        }
        // tiered wave-uniform batches: full-4 / full-2 / full-1 (no masks), then one
        // clamped partial group. deg=17,H=2: one 4-batch + one partial = 20 slots.
        int ng = (ne + EPW - 1) / EPW;
        int g0 = 0;
        for (; (g0 + 4) * EPW <= ne; g0 += 4)
            gather_batch<H, 4, false>(g0, ne, sub, cpo, hsel, so, pw, hb, acc);
        for (; (g0 + 2) * EPW <= ne; g0 += 2)
            gather_batch<H, 2, false>(g0, ne, sub, cpo, hsel, so, pw, hb, acc);
        for (; (g0 + 1) * EPW <= ne; g0 += 1)
            gather_batch<H, 1, false>(g0, ne, sub, cpo, hsel, so, pw, hb, acc);
        if (g0 < ng)
            gather_batch<H, 1, true>(g0, ne, sub, cpo, hsel, so, pw, hb, acc);
    }
    // fold sub-wave partials: lanes sharing cpo sum across sub
#pragma unroll
    for (int o = G; o < 64; o <<= 1)
#pragma unroll
        for (int i = 0; i < 8; i++) acc[i] += __shfl_xor(acc[i], o);
    if (lane < G) {
        float inv = 1.f / ((H == 2 && hsel) ? den[1] : den[0]);
        int c0 = (lane % G) * 8;
        float vout[8];
#pragma unroll
        for (int i = 0; i < 8; i++) {
            vout[i] = acc[i] * inv + bias[c0 + i];
            if (ELU_ACT) vout[i] = vout[i] > 0.f ? vout[i] : expm1f(vout[i]);
        }
        float* zp = z + (size_t)d * (H * 64) + c0;
        *(float4*)zp = make_float4(vout[0], vout[1], vout[2], vout[3]);
        *(float4*)(zp + 4) = make_float4(vout[4], vout[5], vout[6], vout[7]);
    }
}

// =================== decode: dot of endpoint embeddings ===================
__global__ __launch_bounds__(256) void k_decode(const int* __restrict__ eli,
                                                const float* __restrict__ z,
                                                float* __restrict__ out, int EL) {
    int wid = (blockIdx.x * 256 + threadIdx.x) >> 6;
    int lane = threadIdx.x & 63;
    if (wid >= EL) return;
    int a = eli[wid], b = eli[EL + wid];
    float p = z[(size_t)a * 64 + lane] * z[(size_t)b * 64 + lane];
#pragma unroll
    for (int off = 32; off; off >>= 1) p += __shfl_down(p, off);
    if (lane == 0) out[wid] = p;
}

extern "C" void kernel_launch(void* const* d_in, const int* in_sizes, int n_in,
                              void* d_out, int out_size, void* d_ws, size_t ws_size,
                              hipStream_t stream) {
    const float* x   = (const float*)d_in[0];
    const int*   ei  = (const int*)d_in[1];
    const int*   eli = (const int*)d_in[2];
    const float* W1  = (const float*)d_in[3];
    const float* as1 = (const float*)d_in[4];
    const float* ad1 = (const float*)d_in[5];
    const float* b1  = (const float*)d_in[6];
    const float* W2  = (const float*)d_in[7];
    const float* as2 = (const float*)d_in[8];
    const float* ad2 = (const float*)d_in[9];
    const float* b2  = (const float*)d_in[10];

    int N  = in_sizes[0] / 128;
    int E  = in_sizes[1] / 2;
    int EL = in_sizes[2] / 2;
    int ET = E + N;
    int NB = cdiv(N, BSZ);

    char* ws = (char*)d_ws;
    size_t off = 0;
    auto alloc = [&](size_t nbytes) -> void* {
        void* p = ws + off;
        off += (nbytes + 255) & ~(size_t)255;
        return p;
    };
    ushort_t* Hbuf = (ushort_t*)alloc((size_t)N * 128 * 2);  // h1 then h2 (bf16)
    float*    Zbuf = (float*)alloc((size_t)N * 128 * 4);     // z1 then z2 (TMP aliases this)
    float*    AS   = (float*)alloc((size_t)N * 2 * 4);
    float*    AD   = (float*)alloc((size_t)N * 2 * 4);
    int*      OFF  = (int*)alloc((size_t)(N + 1) * 4);
    int*      SSRC = (int*)alloc((size_t)ET * 4);
    int*      BCNT = (int*)alloc((size_t)NB * 4);
    int*      BOFF = (int*)alloc((size_t)(NB + 1) * 4);
    int*      BCUR = (int*)alloc((size_t)NB * 4);
    long long* TMP = (long long*)Zbuf;  // (d,s) pairs; Zbuf unused until k_agg L1

    // ---- CSR build via bucket sort (shared by both layers) ----
    k_zero_int<<<cdiv(NB, 256), 256, 0, stream>>>(BCNT, NB);
    k_bhist<<<256, 256, NB * 4, stream>>>(ei, E, ET, NB, BCNT);
    k_scan_small<<<1, 256, NB * 4, stream>>>(BCNT, NB, BOFF, BCUR, OFF, N, ET);
    k_bscatter<<<cdiv(ET, 4096), 256, 2 * NB * 4, stream>>>(ei, E, ET, NB, BCUR, TMP);
    k_csrfin<<<NB, 256, 0, stream>>>(TMP, BOFF, NB, N, OFF, SSRC);

    // ---- layer 1: heads=2, C=64, ELU ----
    k_gemm<128, 32><<<cdiv(N, 32), 256, 0, stream>>>(x, W1, Hbuf, N);
    k_alpha<2><<<cdiv(N * 2, 4), 256, 0, stream>>>(Hbuf, as1, ad1, AS, AD, N);
    k_agg_fused<2, true><<<cdiv(N, 4), 256, 0, stream>>>(OFF, SSRC, Hbuf, AS, AD, b1, Zbuf, N);

    // ---- layer 2: heads=1, C=64, no activation ----
    k_gemm<64, 64><<<cdiv(N, 64), 256, 0, stream>>>(Zbuf, W2, Hbuf, N);
    k_alpha<1><<<cdiv(N, 4), 256, 0, stream>>>(Hbuf, as2, ad2, AS, AD, N);
    k_agg_fused<1, false><<<cdiv(N, 4), 256, 0, stream>>>(OFF, SSRC, Hbuf, AS, AD, b2, Zbuf, N);

    // ---- decode ----
    k_decode<<<cdiv(EL, 4), 256, 0, stream>>>(eli, Zbuf, (float*)d_out, EL);
}

// Round 9
// 426.671 us; speedup vs baseline: 1.1671x; 1.1668x over previous
//
#include <hip/hip_runtime.h>
#include <hip/hip_bf16.h>

#define NEG_SLOPE 0.2f
#define LRELU(v) ((v) > 0.f ? (v) : NEG_SLOPE * (v))
#define BBITS 7
#define BSZ 128  // nodes per bucket

typedef unsigned short ushort_t;
typedef unsigned int uint_t;

static inline int cdiv(int a, int b) { return (a + b - 1) / b; }

__device__ __forceinline__ float wsum(float v) {
#pragma unroll
    for (int o = 32; o; o >>= 1) v += __shfl_xor(v, o);
    return v;
}
__device__ __forceinline__ ushort_t f2bfbits(float f) {
    __hip_bfloat16 b = __float2bfloat16(f);
    return *reinterpret_cast<ushort_t*>(&b);
}

// =================== bucket-sort CSR build ===================
__global__ __launch_bounds__(256) void k_zero_int(int* p, int n) {
    int i = blockIdx.x * 256 + threadIdx.x;
    if (i < n) p[i] = 0;
}

__global__ __launch_bounds__(256) void k_bhist(const int* __restrict__ ei, int E, int ET, int NB,
                                               int* __restrict__ bcnt) {
    extern __shared__ int hist[];
    for (int i = threadIdx.x; i < NB; i += 256) hist[i] = 0;
    __syncthreads();
    int stride = gridDim.x * 256;
    for (int i = blockIdx.x * 256 + threadIdx.x; i < ET; i += stride) {
        int d = (i < E) ? ei[E + i] : (i - E);  // self loops appended
        atomicAdd(&hist[d >> BBITS], 1);
    }
    __syncthreads();
    for (int i = threadIdx.x; i < NB; i += 256) {
        int c = hist[i];
        if (c) atomicAdd(&bcnt[i], c);
    }
}

__global__ void k_scan_small(const int* __restrict__ bcnt, int NB,
                             int* __restrict__ boff, int* __restrict__ bcur,
                             int* __restrict__ offs, int N, int ET) {
    extern __shared__ int sm[];
    for (int i = threadIdx.x; i < NB; i += blockDim.x) sm[i] = bcnt[i];
    __syncthreads();
    if (threadIdx.x == 0) {
        int run = 0;
        for (int i = 0; i < NB; i++) { int c = sm[i]; sm[i] = run; run += c; }
    }
    __syncthreads();
    for (int i = threadIdx.x; i < NB; i += blockDim.x) { boff[i] = sm[i]; bcur[i] = sm[i]; }
    if (threadIdx.x == 0) { boff[NB] = ET; offs[N] = ET; }
}

__global__ __launch_bounds__(256) void k_bscatter(const int* __restrict__ ei, int E, int ET, int NB,
                                                  int* __restrict__ bcur,
                                                  long long* __restrict__ tmp) {
    extern __shared__ int sm2[];
    int* hist = sm2;
    int* cur = sm2 + NB;
    const int CH = 4096;
    int c0 = blockIdx.x * CH;
    int c1 = min(ET, c0 + CH);
    for (int i = threadIdx.x; i < NB; i += 256) hist[i] = 0;
    __syncthreads();
    for (int i = c0 + threadIdx.x; i < c1; i += 256) {
        int d = (i < E) ? ei[E + i] : (i - E);
        atomicAdd(&hist[d >> BBITS], 1);
    }
    __syncthreads();
    for (int i = threadIdx.x; i < NB; i += 256) {
        int c = hist[i];
        cur[i] = c ? atomicAdd(&bcur[i], c) : 0;
    }
    __syncthreads();
    for (int i = c0 + threadIdx.x; i < c1; i += 256) {
        int s = (i < E) ? ei[i] : (i - E);
        int d = (i < E) ? ei[E + i] : (i - E);
        int pos = atomicAdd(&cur[d >> BBITS], 1);
        tmp[pos] = ((long long)d << 32) | (unsigned)s;
    }
}

__global__ __launch_bounds__(256) void k_csrfin(const long long* __restrict__ tmp,
                                                const int* __restrict__ boff, int NB, int N,
                                                int* __restrict__ offs, int* __restrict__ ssrc) {
    __shared__ int deg[BSZ], cur[BSZ], sc[BSZ];
    int b = blockIdx.x;
    int node0 = b << BBITS;
    int nn = min(BSZ, N - node0);
    int r0 = boff[b], r1 = boff[b + 1];
    int t = threadIdx.x;
    if (t < BSZ) deg[t] = 0;
    __syncthreads();
    for (int i = r0 + t; i < r1; i += 256) {
        int d = (int)(tmp[i] >> 32);
        atomicAdd(&deg[d - node0], 1);
    }
    __syncthreads();
    if (t < BSZ) sc[t] = deg[t];
    __syncthreads();
    for (int o = 1; o < BSZ; o <<= 1) {
        int v = 0;
        if (t < BSZ && t >= o) v = sc[t - o];
        __syncthreads();
        if (t < BSZ) sc[t] += v;
        __syncthreads();
    }
    if (t < BSZ) {
        int ex = sc[t] - deg[t];
        cur[t] = r0 + ex;
        if (t < nn) offs[node0 + t] = r0 + ex;
    }
    __syncthreads();
    for (int i = r0 + t; i < r1; i += 256) {
        long long v = tmp[i];
        int d = (int)(v >> 32);
        int s = (int)(v & 0xffffffffLL);
        int pos = atomicAdd(&cur[d - node0], 1);
        ssrc[pos] = s;
    }
}

// ==== GEMM + fused alpha: h[N,M] = x[N,128]@W (bf16 out), as/ad via register shfl ====
// Threads owning one output row are 16 consecutive lanes -> width-16 shfl reduction,
// no LDS, no atomics (cost of the failed R5 fusion).
template <int M, int TR, int H>
__global__ __launch_bounds__(256) void k_gemm_alpha(const float* __restrict__ x,
                                                    const float* __restrict__ W,
                                                    const float* __restrict__ a_src,
                                                    const float* __restrict__ a_dst,
                                                    ushort_t* __restrict__ h,
                                                    float* __restrict__ as, float* __restrict__ ad,
                                                    int N) {
    __shared__ float xs[128 * TR];  // xs[k][r], full K staged once
    __shared__ float ws[64 * M];    // ws[k][j], one 64-row half of W at a time
    int t = threadIdx.x;
    int row0 = blockIdx.x * TR;

    {   // load x tile transposed
        int r = t % TR;
        int kv0 = t / TR;
        const int GK = 256 / TR;
        int row = row0 + r;
        for (int kv = kv0; kv < 32; kv += GK) {
            float4 v = make_float4(0.f, 0.f, 0.f, 0.f);
            if (row < N) v = *(const float4*)(x + (size_t)row * 128 + kv * 4);
            xs[(kv * 4 + 0) * TR + r] = v.x;
            xs[(kv * 4 + 1) * TR + r] = v.y;
            xs[(kv * 4 + 2) * TR + r] = v.z;
            xs[(kv * 4 + 3) * TR + r] = v.w;
        }
    }

    constexpr int CQ = M / 4;
    int tx = t % CQ, ty = t / CQ;
    int j0 = tx * 4, r0 = ty * 4;
    float acc[4][4];
#pragma unroll
    for (int a = 0; a < 4; a++)
#pragma unroll
        for (int b = 0; b < 4; b++) acc[a][b] = 0.f;

    for (int ks = 0; ks < 128; ks += 64) {
        __syncthreads();
        const float4* wg = (const float4*)(W + (size_t)ks * M);
        float4* wl = (float4*)ws;
        for (int i = t; i < 64 * M / 4; i += 256) wl[i] = wg[i];
        __syncthreads();
#pragma unroll 8
        for (int k = 0; k < 64; k++) {
            float4 xv = *(const float4*)(xs + (ks + k) * TR + r0);
            float4 wv = *(const float4*)(ws + k * M + j0);
            float xr[4] = {xv.x, xv.y, xv.z, xv.w};
            float wr[4] = {wv.x, wv.y, wv.z, wv.w};
#pragma unroll
            for (int a = 0; a < 4; a++)
#pragma unroll
                for (int b = 0; b < 4; b++) acc[a][b] += xr[a] * wr[b];
        }
    }
    float4 asv = *(const float4*)(a_src + j0);
    float4 adv = *(const float4*)(a_dst + j0);
#pragma unroll
    for (int a = 0; a < 4; a++) {
        int row = row0 + r0 + a;
        if (row < N) {
            ushort4 pk;
            pk.x = f2bfbits(acc[a][0]);
            pk.y = f2bfbits(acc[a][1]);
            pk.z = f2bfbits(acc[a][2]);
            pk.w = f2bfbits(acc[a][3]);
            *(ushort4*)(h + (size_t)row * M + j0) = pk;
        }
        float ps = acc[a][0] * asv.x + acc[a][1] * asv.y + acc[a][2] * asv.z + acc[a][3] * asv.w;
        float pd = acc[a][0] * adv.x + acc[a][1] * adv.y + acc[a][2] * adv.z + acc[a][3] * adv.w;
#pragma unroll
        for (int o = 8; o; o >>= 1) {
            ps += __shfl_down(ps, o, 16);
            pd += __shfl_down(pd, o, 16);
        }
        if ((tx & 15) == 0 && row < N) {
            int head = (H == 2) ? (tx >> 4) : 0;
            as[(size_t)row * H + head] = ps;
            ad[(size_t)row * H + head] = pd;
        }
    }
}

// ======= fused softmax + aggregation (R6 structure, byte-offset shfl) =======
template <int H, bool ELU_ACT>
__global__ __launch_bounds__(256) void k_agg_fused(const int* __restrict__ offs,
                                                   const int* __restrict__ ssrc,
                                                   const ushort_t* __restrict__ h,
                                                   const float* __restrict__ as,
                                                   const float* __restrict__ ad,
                                                   const float* __restrict__ bias,
                                                   float* __restrict__ z, int N) {
    constexpr int G = 8 * H;     // lanes per source row (16 B each)
    constexpr int EPW = 64 / G;  // edges per wave-wide load
    constexpr int NBG = 4;       // group-loads batched in flight
    constexpr int RB = H * 128;  // row bytes (bf16)
    __shared__ float pl[4][64 * H];
    int d = (blockIdx.x * 256 + threadIdx.x) >> 6;
    int lane = threadIdx.x & 63;
    float* pw = pl[threadIdx.x >> 6];
    if (d >= N) return;
    int cpos = lane % G;         // 16B chunk index within row
    int sub = lane / G;          // which edge of the load group
    int hself = (H == 2) ? (cpos >> 3) : 0;
    const char* hb = (const char*)h;

    float adh[H], den[H];
#pragma unroll
    for (int hh = 0; hh < H; hh++) { adh[hh] = ad[(size_t)d * H + hh]; den[hh] = 0.f; }
    float acc[8];
#pragma unroll
    for (int i = 0; i < 8; i++) acc[i] = 0.f;

    int e0 = offs[d], e1 = offs[d + 1];
    for (int cb = e0; cb < e1; cb += 64) {
        int ne = min(64, e1 - cb);
        unsigned so = 0;
        float p[H];
#pragma unroll
        for (int hh = 0; hh < H; hh++) p[hh] = 0.f;
        if (lane < ne) {
            int s_l = ssrc[cb + lane];
            so = (unsigned)s_l * RB;  // pre-scaled 32-bit byte offset
            if (H == 2) {
                float2 av = ((const float2*)as)[s_l];
                p[0] = __expf(LRELU(av.x + adh[0]));
                p[1] = __expf(LRELU(av.y + adh[1]));
            } else {
                p[0] = __expf(LRELU(as[s_l] + adh[0]));
            }
        }
#pragma unroll
        for (int hh = 0; hh < H; hh++) den[hh] += wsum(p[hh]);
        if (H == 2) {
            pw[lane * 2] = p[0];
            pw[lane * 2 + 1] = p[1];
        } else {
            pw[lane] = p[0];
        }
        // gather: NBG group-loads in flight, masked; fixed stride (R6 structure)
        for (int j = 0; j < ne; j += NBG * EPW) {
            uint4 hv[NBG];
            int el[NBG];
            bool ok[NBG];
#pragma unroll
            for (int g = 0; g < NBG; g++) {
                int eidx = j + g * EPW + sub;
                el[g] = eidx & 63;
                ok[g] = eidx < ne;
                unsigned so_e = (unsigned)__shfl((int)so, el[g]);
                hv[g] = make_uint4(0u, 0u, 0u, 0u);
                if (ok[g]) hv[g] = *(const uint4*)(hb + (so_e + cpos * 16));
            }
#pragma unroll
            for (int g = 0; g < NBG; g++) {
                float pv = ok[g] ? pw[el[g] * H + hself] : 0.f;
                acc[0] += pv * __uint_as_float(hv[g].x << 16);
                acc[1] += pv * __uint_as_float(hv[g].x & 0xffff0000u);
                acc[2] += pv * __uint_as_float(hv[g].y << 16);
                acc[3] += pv * __uint_as_float(hv[g].y & 0xffff0000u);
                acc[4] += pv * __uint_as_float(hv[g].z << 16);
                acc[5] += pv * __uint_as_float(hv[g].z & 0xffff0000u);
                acc[6] += pv * __uint_as_float(hv[g].w << 16);
                acc[7] += pv * __uint_as_float(hv[g].w & 0xffff0000u);
            }
        }
    }
    // fold sub-wave partials: lanes sharing cpos sum across sub
#pragma unroll
    for (int o = G; o < 64; o <<= 1)
#pragma unroll
        for (int i = 0; i < 8; i++) acc[i] += __shfl_xor(acc[i], o);
    if (lane < G) {
        float inv = 1.f / ((H == 2 && hself) ? den[1] : den[0]);
        float vout[8];
#pragma unroll
        for (int i = 0; i < 8; i++) {
            vout[i] = acc[i] * inv + bias[cpos * 8 + i];
            if (ELU_ACT) vout[i] = vout[i] > 0.f ? vout[i] : expm1f(vout[i]);
        }
        float* zp = z + (size_t)d * (H * 64) + cpos * 8;
        *(float4*)zp = make_float4(vout[0], vout[1], vout[2], vout[3]);
        *(float4*)(zp + 4) = make_float4(vout[4], vout[5], vout[6], vout[7]);
    }
}

// =================== decode: 2 pairs per wave, float2 per lane ===================
__global__ __launch_bounds__(256) void k_decode(const int* __restrict__ eli,
                                                const float* __restrict__ z,
                                                float* __restrict__ out, int EL) {
    int wid = (blockIdx.x * 256 + threadIdx.x) >> 6;
    int lane = threadIdx.x & 63;
    int pi = wid * 2 + (lane >> 5);
    if (pi >= EL) return;
    int hl = lane & 31;
    int a = eli[pi], b = eli[EL + pi];
    float2 za = ((const float2*)(z + (size_t)a * 64))[hl];
    float2 zb = ((const float2*)(z + (size_t)b * 64))[hl];
    float p = za.x * zb.x + za.y * zb.y;
#pragma unroll
    for (int o = 16; o; o >>= 1) p += __shfl_down(p, o, 32);
    if (hl == 0) out[pi] = p;
}

extern "C" void kernel_launch(void* const* d_in, const int* in_sizes, int n_in,
                              void* d_out, int out_size, void* d_ws, size_t ws_size,
                              hipStream_t stream) {
    const float* x   = (const float*)d_in[0];
    const int*   ei  = (const int*)d_in[1];
    const int*   eli = (const int*)d_in[2];
    const float* W1  = (const float*)d_in[3];
    const float* as1 = (const float*)d_in[4];
    const float* ad1 = (const float*)d_in[5];
    const float* b1  = (const float*)d_in[6];
    const float* W2  = (const float*)d_in[7];
    const float* as2 = (const float*)d_in[8];
    const float* ad2 = (const float*)d_in[9];
    const float* b2  = (const float*)d_in[10];

    int N  = in_sizes[0] / 128;
    int E  = in_sizes[1] / 2;
    int EL = in_sizes[2] / 2;
    int ET = E + N;
    int NB = cdiv(N, BSZ);

    char* ws = (char*)d_ws;
    size_t off = 0;
    auto alloc = [&](size_t nbytes) -> void* {
        void* p = ws + off;
        off += (nbytes + 255) & ~(size_t)255;
        return p;
    };
    ushort_t* Hbuf = (ushort_t*)alloc((size_t)N * 128 * 2);  // h1 then h2 (bf16)
    float*    Zbuf = (float*)alloc((size_t)N * 128 * 4);     // z1 then z2 (TMP aliases this)
    float*    AS   = (float*)alloc((size_t)N * 2 * 4);
    float*    AD   = (float*)alloc((size_t)N * 2 * 4);
    int*      OFF  = (int*)alloc((size_t)(N + 1) * 4);
    int*      SSRC = (int*)alloc((size_t)ET * 4);
    int*      BCNT = (int*)alloc((size_t)NB * 4);
    int*      BOFF = (int*)alloc((size_t)(NB + 1) * 4);
    int*      BCUR = (int*)alloc((size_t)NB * 4);
    long long* TMP = (long long*)Zbuf;  // (d,s) pairs; Zbuf unused until k_agg L1

    // ---- CSR build via bucket sort (shared by both layers) ----
    k_zero_int<<<cdiv(NB, 256), 256, 0, stream>>>(BCNT, NB);
    k_bhist<<<256, 256, NB * 4, stream>>>(ei, E, ET, NB, BCNT);
    k_scan_small<<<1, 256, NB * 4, stream>>>(BCNT, NB, BOFF, BCUR, OFF, N, ET);
    k_bscatter<<<cdiv(ET, 4096), 256, 2 * NB * 4, stream>>>(ei, E, ET, NB, BCUR, TMP);
    k_csrfin<<<NB, 256, 0, stream>>>(TMP, BOFF, NB, N, OFF, SSRC);

    // ---- layer 1: heads=2, C=64, ELU ----
    k_gemm_alpha<128, 32, 2><<<cdiv(N, 32), 256, 0, stream>>>(x, W1, as1, ad1, Hbuf, AS, AD, N);
    k_agg_fused<2, true><<<cdiv(N, 4), 256, 0, stream>>>(OFF, SSRC, Hbuf, AS, AD, b1, Zbuf, N);

    // ---- layer 2: heads=1, C=64, no activation ----
    k_gemm_alpha<64, 64, 1><<<cdiv(N, 64), 256, 0, stream>>>(Zbuf, W2, as2, ad2, Hbuf, AS, AD, N);
    k_agg_fused<1, false><<<cdiv(N, 4), 256, 0, stream>>>(OFF, SSRC, Hbuf, AS, AD, b2, Zbuf, N);

    // ---- decode ----
    k_decode<<<cdiv(EL, 8), 256, 0, stream>>>(eli, Zbuf, (float*)d_out, EL);
}

// Round 10
// 372.542 us; speedup vs baseline: 1.3367x; 1.1453x over previous
//
#include <hip/hip_runtime.h>
#include <hip/hip_bf16.h>

#define NEG_SLOPE 0.2f
#define LRELU(v) ((v) > 0.f ? (v) : NEG_SLOPE * (v))
#define BBITS 7
#define BSZ 128  // nodes per bucket

typedef unsigned short ushort_t;
typedef unsigned int uint_t;
typedef float v2f __attribute__((ext_vector_type(2)));
typedef float f32x4 __attribute__((ext_vector_type(4)));
typedef short bf16x8 __attribute__((ext_vector_type(8)));

static inline int cdiv(int a, int b) { return (a + b - 1) / b; }

__device__ __forceinline__ float wsum(float v) {
#pragma unroll
    for (int o = 32; o; o >>= 1) v += __shfl_xor(v, o);
    return v;
}
__device__ __forceinline__ ushort_t f2bfbits(float f) {
    __hip_bfloat16 b = __float2bfloat16(f);
    return *reinterpret_cast<ushort_t*>(&b);
}

// =================== bucket-sort CSR build ===================
__global__ __launch_bounds__(256) void k_zero_int(int* p, int n) {
    int i = blockIdx.x * 256 + threadIdx.x;
    if (i < n) p[i] = 0;
}

__global__ __launch_bounds__(256) void k_bhist(const int* __restrict__ ei, int E, int ET, int NB,
                                               int* __restrict__ bcnt) {
    extern __shared__ int hist[];
    for (int i = threadIdx.x; i < NB; i += 256) hist[i] = 0;
    __syncthreads();
    int stride = gridDim.x * 256;
    for (int i = blockIdx.x * 256 + threadIdx.x; i < ET; i += stride) {
        int d = (i < E) ? ei[E + i] : (i - E);  // self loops appended
        atomicAdd(&hist[d >> BBITS], 1);
    }
    __syncthreads();
    for (int i = threadIdx.x; i < NB; i += 256) {
        int c = hist[i];
        if (c) atomicAdd(&bcnt[i], c);
    }
}

__global__ void k_scan_small(const int* __restrict__ bcnt, int NB,
                             int* __restrict__ boff, int* __restrict__ bcur,
                             int* __restrict__ offs, int N, int ET) {
    extern __shared__ int sm[];
    for (int i = threadIdx.x; i < NB; i += blockDim.x) sm[i] = bcnt[i];
    __syncthreads();
    if (threadIdx.x == 0) {
        int run = 0;
        for (int i = 0; i < NB; i++) { int c = sm[i]; sm[i] = run; run += c; }
    }
    __syncthreads();
    for (int i = threadIdx.x; i < NB; i += blockDim.x) { boff[i] = sm[i]; bcur[i] = sm[i]; }
    if (threadIdx.x == 0) { boff[NB] = ET; offs[N] = ET; }
}

__global__ __launch_bounds__(256) void k_bscatter(const int* __restrict__ ei, int E, int ET, int NB,
                                                  int* __restrict__ bcur,
                                                  long long* __restrict__ tmp) {
    extern __shared__ int sm2[];
    int* hist = sm2;
    int* cur = sm2 + NB;
    const int CH = 4096;
    int c0 = blockIdx.x * CH;
    int c1 = min(ET, c0 + CH);
    for (int i = threadIdx.x; i < NB; i += 256) hist[i] = 0;
    __syncthreads();
    for (int i = c0 + threadIdx.x; i < c1; i += 256) {
        int d = (i < E) ? ei[E + i] : (i - E);
        atomicAdd(&hist[d >> BBITS], 1);
    }
    __syncthreads();
    for (int i = threadIdx.x; i < NB; i += 256) {
        int c = hist[i];
        cur[i] = c ? atomicAdd(&bcur[i], c) : 0;
    }
    __syncthreads();
    for (int i = c0 + threadIdx.x; i < c1; i += 256) {
        int s = (i < E) ? ei[i] : (i - E);
        int d = (i < E) ? ei[E + i] : (i - E);
        int pos = atomicAdd(&cur[d >> BBITS], 1);
        tmp[pos] = ((long long)d << 32) | (unsigned)s;
    }
}

__global__ __launch_bounds__(256) void k_csrfin(const long long* __restrict__ tmp,
                                                const int* __restrict__ boff, int NB, int N,
                                                int* __restrict__ offs, int* __restrict__ ssrc) {
    __shared__ int deg[BSZ], cur[BSZ], sc[BSZ];
    int b = blockIdx.x;
    int node0 = b << BBITS;
    int nn = min(BSZ, N - node0);
    int r0 = boff[b], r1 = boff[b + 1];
    int t = threadIdx.x;
    if (t < BSZ) deg[t] = 0;
    __syncthreads();
    for (int i = r0 + t; i < r1; i += 256) {
        int d = (int)(tmp[i] >> 32);
        atomicAdd(&deg[d - node0], 1);
    }
    __syncthreads();
    if (t < BSZ) sc[t] = deg[t];
    __syncthreads();
    for (int o = 1; o < BSZ; o <<= 1) {
        int v = 0;
        if (t < BSZ && t >= o) v = sc[t - o];
        __syncthreads();
        if (t < BSZ) sc[t] += v;
        __syncthreads();
    }
    if (t < BSZ) {
        int ex = sc[t] - deg[t];
        cur[t] = r0 + ex;
        if (t < nn) offs[node0 + t] = r0 + ex;
    }
    __syncthreads();
    for (int i = r0 + t; i < r1; i += 256) {
        long long v = tmp[i];
        int d = (int)(v >> 32);
        int s = (int)(v & 0xffffffffLL);
        int pos = atomicAdd(&cur[d - node0], 1);
        ssrc[pos] = s;
    }
}

// ========== transpose weights to bf16: Wt[n][k] = bf16(W[k][n]) ==========
__global__ __launch_bounds__(256) void k_wt(const float* __restrict__ W, ushort_t* __restrict__ Wt,
                                            int K, int M) {
    for (int idx = blockIdx.x * 256 + threadIdx.x; idx < K * M; idx += gridDim.x * 256) {
        int k = idx / M, n = idx % M;
        Wt[n * K + k] = f2bfbits(W[idx]);
    }
}

// ===== MFMA GEMM + fused alpha: h[N,M](bf16) = x[N,128] @ W[128,M]; as/ad = h·a_* =====
// Block = 256 thr = 4 waves, 64 rows; wave w owns rows row0+w*16..+15.
// A-frag: x fp32 loaded & packed in-register (A[m=lane&15][k=quad*8+j]).
// B-frag: global Wt bf16 (B[k=quad*8+j][n=lane&15]) — L2-broadcast, no LDS.
// C/D: col=lane&15, row=quad*4+reg  [verified m89 mapping].
template <int M, int H>
__global__ __launch_bounds__(256) void k_gemm_mfma(const float* __restrict__ x,
                                                   const ushort_t* __restrict__ Wt,
                                                   const float* __restrict__ a_src,
                                                   const float* __restrict__ a_dst,
                                                   ushort_t* __restrict__ h,
                                                   float* __restrict__ as, float* __restrict__ ad,
                                                   int N) {
    constexpr int T = M / 16;  // col tiles
    int t = threadIdx.x;
    int w = t >> 6;
    int lane = t & 63;
    int ln = lane & 15;
    int q = lane >> 4;
    int rowA = blockIdx.x * 64 + w * 16 + ln;   // row this lane supplies to A
    int rowD0 = blockIdx.x * 64 + w * 16 + q * 4;  // first D row for this lane

    f32x4 acc[T];
#pragma unroll
    for (int i = 0; i < T; i++) acc[i] = (f32x4){0.f, 0.f, 0.f, 0.f};

#pragma unroll
    for (int kc = 0; kc < 4; kc++) {
        // A fragment: 8 floats -> 8 bf16
        bf16x8 afrag;
        float xv[8];
        if (rowA < N) {
            float4 v0 = *(const float4*)(x + (size_t)rowA * 128 + kc * 32 + q * 8);
            float4 v1 = *(const float4*)(x + (size_t)rowA * 128 + kc * 32 + q * 8 + 4);
            xv[0] = v0.x; xv[1] = v0.y; xv[2] = v0.z; xv[3] = v0.w;
            xv[4] = v1.x; xv[5] = v1.y; xv[6] = v1.z; xv[7] = v1.w;
        } else {
#pragma unroll
            for (int j = 0; j < 8; j++) xv[j] = 0.f;
        }
#pragma unroll
        for (int j = 0; j < 8; j++) afrag[j] = (short)f2bfbits(xv[j]);
        // B fragments per col tile + MFMA
#pragma unroll
        for (int tt = 0; tt < T; tt++) {
            bf16x8 bfrag = *(const bf16x8*)(Wt + (size_t)(tt * 16 + ln) * 128 + kc * 32 + q * 8);
            acc[tt] = __builtin_amdgcn_mfma_f32_16x16x32_bf16(afrag, bfrag, acc[tt], 0, 0, 0);
        }
    }

    // store h (bf16): lane writes rows rowD0+r, col tt*16+ln
#pragma unroll
    for (int tt = 0; tt < T; tt++)
#pragma unroll
        for (int r = 0; r < 4; r++) {
            int row = rowD0 + r;
            if (row < N) h[(size_t)row * M + tt * 16 + ln] = f2bfbits(acc[tt][r]);
        }

    // fused alpha: per reg r, row rowD0+r; partial over this lane's cols, reduce width-16
    float avs[T], avd[T];
#pragma unroll
    for (int tt = 0; tt < T; tt++) {
        avs[tt] = a_src[tt * 16 + ln];
        avd[tt] = a_dst[tt * 16 + ln];
    }
#pragma unroll
    for (int r = 0; r < 4; r++) {
        int row = rowD0 + r;
        if (H == 2) {
            float ps0 = 0.f, ps1 = 0.f, pd0 = 0.f, pd1 = 0.f;
#pragma unroll
            for (int tt = 0; tt < T / 2; tt++) { ps0 += acc[tt][r] * avs[tt]; pd0 += acc[tt][r] * avd[tt]; }
#pragma unroll
            for (int tt = T / 2; tt < T; tt++) { ps1 += acc[tt][r] * avs[tt]; pd1 += acc[tt][r] * avd[tt]; }
#pragma unroll
            for (int o = 8; o; o >>= 1) {
                ps0 += __shfl_down(ps0, o, 16); pd0 += __shfl_down(pd0, o, 16);
                ps1 += __shfl_down(ps1, o, 16); pd1 += __shfl_down(pd1, o, 16);
            }
            if (ln == 0 && row < N) {
                as[(size_t)row * 2] = ps0; as[(size_t)row * 2 + 1] = ps1;
                ad[(size_t)row * 2] = pd0; ad[(size_t)row * 2 + 1] = pd1;
            }
        } else {
            float ps = 0.f, pd = 0.f;
#pragma unroll
            for (int tt = 0; tt < T; tt++) { ps += acc[tt][r] * avs[tt]; pd += acc[tt][r] * avd[tt]; }
#pragma unroll
            for (int o = 8; o; o >>= 1) {
                ps += __shfl_down(ps, o, 16); pd += __shfl_down(pd, o, 16);
            }
            if (ln == 0 && row < N) { as[row] = ps; ad[row] = pd; }
        }
    }
}

// ======= fused softmax + aggregation (R6 structure, byte-offset shfl, pk-f32 accum) =======
template <int H, bool ELU_ACT>
__global__ __launch_bounds__(256) void k_agg_fused(const int* __restrict__ offs,
                                                   const int* __restrict__ ssrc,
                                                   const ushort_t* __restrict__ h,
                                                   const float* __restrict__ as,
                                                   const float* __restrict__ ad,
                                                   const float* __restrict__ bias,
                                                   float* __restrict__ z, int N) {
    constexpr int G = 8 * H;     // lanes per source row (16 B each)
    constexpr int EPW = 64 / G;  // edges per wave-wide load
    constexpr int NBG = 4;       // group-loads batched in flight
    constexpr int RB = H * 128;  // row bytes (bf16)
    __shared__ float pl[4][64 * H];
    int d = (blockIdx.x * 256 + threadIdx.x) >> 6;
    int lane = threadIdx.x & 63;
    float* pw = pl[threadIdx.x >> 6];
    if (d >= N) return;
    int cpos = lane % G;         // 16B chunk index within row
    int sub = lane / G;          // which edge of the load group
    int hself = (H == 2) ? (cpos >> 3) : 0;
    const char* hb = (const char*)h;

    float adh[H], den[H];
#pragma unroll
    for (int hh = 0; hh < H; hh++) { adh[hh] = ad[(size_t)d * H + hh]; den[hh] = 0.f; }
    v2f acc2[4];
#pragma unroll
    for (int i = 0; i < 4; i++) acc2[i] = (v2f){0.f, 0.f};

    int e0 = offs[d], e1 = offs[d + 1];
    for (int cb = e0; cb < e1; cb += 64) {
        int ne = min(64, e1 - cb);
        unsigned so = 0;
        float p[H];
#pragma unroll
        for (int hh = 0; hh < H; hh++) p[hh] = 0.f;
        if (lane < ne) {
            int s_l = ssrc[cb + lane];
            so = (unsigned)s_l * RB;  // pre-scaled 32-bit byte offset
            if (H == 2) {
                float2 av = ((const float2*)as)[s_l];
                p[0] = __expf(LRELU(av.x + adh[0]));
                p[1] = __expf(LRELU(av.y + adh[1]));
            } else {
                p[0] = __expf(LRELU(as[s_l] + adh[0]));
            }
        }
#pragma unroll
        for (int hh = 0; hh < H; hh++) den[hh] += wsum(p[hh]);
        if (H == 2) {
            pw[lane * 2] = p[0];
            pw[lane * 2 + 1] = p[1];
        } else {
            pw[lane] = p[0];
        }
        // gather: NBG group-loads in flight, masked; fixed stride (R6 structure)
        for (int j = 0; j < ne; j += NBG * EPW) {
            uint4 hv[NBG];
            int el[NBG];
            bool ok[NBG];
#pragma unroll
            for (int g = 0; g < NBG; g++) {
                int eidx = j + g * EPW + sub;
                el[g] = eidx & 63;
                ok[g] = eidx < ne;
                unsigned so_e = (unsigned)__shfl((int)so, el[g]);
                hv[g] = make_uint4(0u, 0u, 0u, 0u);
                if (ok[g]) hv[g] = *(const uint4*)(hb + (so_e + cpos * 16));
            }
#pragma unroll
            for (int g = 0; g < NBG; g++) {
                float pvs = ok[g] ? pw[el[g] * H + hself] : 0.f;
                v2f pv = {pvs, pvs};
                v2f t0 = {__uint_as_float(hv[g].x << 16), __uint_as_float(hv[g].x & 0xffff0000u)};
                v2f t1 = {__uint_as_float(hv[g].y << 16), __uint_as_float(hv[g].y & 0xffff0000u)};
                v2f t2 = {__uint_as_float(hv[g].z << 16), __uint_as_float(hv[g].z & 0xffff0000u)};
                v2f t3 = {__uint_as_float(hv[g].w << 16), __uint_as_float(hv[g].w & 0xffff0000u)};
                acc2[0] += pv * t0;
                acc2[1] += pv * t1;
                acc2[2] += pv * t2;
                acc2[3] += pv * t3;
            }
        }
    }
    // fold sub-wave partials: lanes sharing cpos sum across sub
#pragma unroll
    for (int o = G; o < 64; o <<= 1)
#pragma unroll
        for (int i = 0; i < 4; i++) {
            acc2[i][0] += __shfl_xor(acc2[i][0], o);
            acc2[i][1] += __shfl_xor(acc2[i][1], o);
        }
    if (lane < G) {
        float inv = 1.f / ((H == 2 && hself) ? den[1] : den[0]);
        float vout[8];
#pragma unroll
        for (int i = 0; i < 4; i++) {
            vout[2 * i] = acc2[i][0] * inv + bias[cpos * 8 + 2 * i];
            vout[2 * i + 1] = acc2[i][1] * inv + bias[cpos * 8 + 2 * i + 1];
        }
        if (ELU_ACT) {
#pragma unroll
            for (int i = 0; i < 8; i++) vout[i] = vout[i] > 0.f ? vout[i] : expm1f(vout[i]);
        }
        float* zp = z + (size_t)d * (H * 64) + cpos * 8;
        *(float4*)zp = make_float4(vout[0], vout[1], vout[2], vout[3]);
        *(float4*)(zp + 4) = make_float4(vout[4], vout[5], vout[6], vout[7]);
    }
}

// =================== decode: 2 pairs per wave, float2 per lane ===================
__global__ __launch_bounds__(256) void k_decode(const int* __restrict__ eli,
                                                const float* __restrict__ z,
                                                float* __restrict__ out, int EL) {
    int wid = (blockIdx.x * 256 + threadIdx.x) >> 6;
    int lane = threadIdx.x & 63;
    int pi = wid * 2 + (lane >> 5);
    if (pi >= EL) return;
    int hl = lane & 31;
    int a = eli[pi], b = eli[EL + pi];
    float2 za = ((const float2*)(z + (size_t)a * 64))[hl];
    float2 zb = ((const float2*)(z + (size_t)b * 64))[hl];
    float p = za.x * zb.x + za.y * zb.y;
#pragma unroll
    for (int o = 16; o; o >>= 1) p += __shfl_down(p, o, 32);
    if (hl == 0) out[pi] = p;
}

extern "C" void kernel_launch(void* const* d_in, const int* in_sizes, int n_in,
                              void* d_out, int out_size, void* d_ws, size_t ws_size,
                              hipStream_t stream) {
    const float* x   = (const float*)d_in[0];
    const int*   ei  = (const int*)d_in[1];
    const int*   eli = (const int*)d_in[2];
    const float* W1  = (const float*)d_in[3];
    const float* as1 = (const float*)d_in[4];
    const float* ad1 = (const float*)d_in[5];
    const float* b1  = (const float*)d_in[6];
    const float* W2  = (const float*)d_in[7];
    const float* as2 = (const float*)d_in[8];
    const float* ad2 = (const float*)d_in[9];
    const float* b2  = (const float*)d_in[10];

    int N  = in_sizes[0] / 128;
    int E  = in_sizes[1] / 2;
    int EL = in_sizes[2] / 2;
    int ET = E + N;
    int NB = cdiv(N, BSZ);

    char* ws = (char*)d_ws;
    size_t off = 0;
    auto alloc = [&](size_t nbytes) -> void* {
        void* p = ws + off;
        off += (nbytes + 255) & ~(size_t)255;
        return p;
    };
    ushort_t* Hbuf = (ushort_t*)alloc((size_t)N * 128 * 2);  // h1 then h2 (bf16)
    float*    Zbuf = (float*)alloc((size_t)N * 128 * 4);     // z1 then z2 (TMP aliases this)
    float*    AS   = (float*)alloc((size_t)N * 2 * 4);
    float*    AD   = (float*)alloc((size_t)N * 2 * 4);
    int*      OFF  = (int*)alloc((size_t)(N + 1) * 4);
    int*      SSRC = (int*)alloc((size_t)ET * 4);
    int*      BCNT = (int*)alloc((size_t)NB * 4);
    int*      BOFF = (int*)alloc((size_t)(NB + 1) * 4);
    int*      BCUR = (int*)alloc((size_t)NB * 4);
    ushort_t* WT1  = (ushort_t*)alloc(128 * 128 * 2);
    ushort_t* WT2  = (ushort_t*)alloc(64 * 128 * 2);
    long long* TMP = (long long*)Zbuf;  // (d,s) pairs; Zbuf unused until k_agg L1

    // ---- CSR build via bucket sort (shared by both layers) ----
    k_zero_int<<<cdiv(NB, 256), 256, 0, stream>>>(BCNT, NB);
    k_bhist<<<256, 256, NB * 4, stream>>>(ei, E, ET, NB, BCNT);
    k_scan_small<<<1, 256, NB * 4, stream>>>(BCNT, NB, BOFF, BCUR, OFF, N, ET);
    k_bscatter<<<cdiv(ET, 4096), 256, 2 * NB * 4, stream>>>(ei, E, ET, NB, BCUR, TMP);
    k_csrfin<<<NB, 256, 0, stream>>>(TMP, BOFF, NB, N, OFF, SSRC);

    // ---- weight transposes (bf16) ----
    k_wt<<<32, 256, 0, stream>>>(W1, WT1, 128, 128);
    k_wt<<<16, 256, 0, stream>>>(W2, WT2, 128, 64);

    // ---- layer 1: heads=2, C=64, ELU ----
    k_gemm_mfma<128, 2><<<cdiv(N, 64), 256, 0, stream>>>(x, WT1, as1, ad1, Hbuf, AS, AD, N);
    k_agg_fused<2, true><<<cdiv(N, 4), 256, 0, stream>>>(OFF, SSRC, Hbuf, AS, AD, b1, Zbuf, N);

    // ---- layer 2: heads=1, C=64, no activation ----
    k_gemm_mfma<64, 1><<<cdiv(N, 64), 256, 0, stream>>>(Zbuf, WT2, as2, ad2, Hbuf, AS, AD, N);
    k_agg_fused<1, false><<<cdiv(N, 4), 256, 0, stream>>>(OFF, SSRC, Hbuf, AS, AD, b2, Zbuf, N);

    // ---- decode ----
    k_decode<<<cdiv(EL, 8), 256, 0, stream>>>(eli, Zbuf, (float*)d_out, EL);
}

// Round 11
// 365.090 us; speedup vs baseline: 1.3640x; 1.0204x over previous
//
#include <hip/hip_runtime.h>
#include <hip/hip_bf16.h>

#define NEG_SLOPE 0.2f
#define LRELU(v) ((v) > 0.f ? (v) : NEG_SLOPE * (v))
#define BBITS 7
#define BSZ 128  // nodes per bucket

typedef unsigned short ushort_t;
typedef unsigned int uint_t;
typedef float v2f __attribute__((ext_vector_type(2)));
typedef float f32x4 __attribute__((ext_vector_type(4)));
typedef short bf16x8 __attribute__((ext_vector_type(8)));

static inline int cdiv(int a, int b) { return (a + b - 1) / b; }

__device__ __forceinline__ float wsum(float v) {
#pragma unroll
    for (int o = 32; o; o >>= 1) v += __shfl_xor(v, o);
    return v;
}
__device__ __forceinline__ ushort_t f2bfbits(float f) {
    __hip_bfloat16 b = __float2bfloat16(f);
    return *reinterpret_cast<ushort_t*>(&b);
}

// =================== bucket-sort CSR build ===================
__global__ __launch_bounds__(256) void k_zero_int(int* p, int n) {
    int i = blockIdx.x * 256 + threadIdx.x;
    if (i < n) p[i] = 0;
}

__global__ __launch_bounds__(256) void k_bhist(const int* __restrict__ ei, int E, int ET, int NB,
                                               int* __restrict__ bcnt) {
    extern __shared__ int hist[];
    for (int i = threadIdx.x; i < NB; i += 256) hist[i] = 0;
    __syncthreads();
    int stride = gridDim.x * 256;
    for (int i = blockIdx.x * 256 + threadIdx.x; i < ET; i += stride) {
        int d = (i < E) ? ei[E + i] : (i - E);  // self loops appended
        atomicAdd(&hist[d >> BBITS], 1);
    }
    __syncthreads();
    for (int i = threadIdx.x; i < NB; i += 256) {
        int c = hist[i];
        if (c) atomicAdd(&bcnt[i], c);
    }
}

__global__ void k_scan_small(const int* __restrict__ bcnt, int NB,
                             int* __restrict__ boff, int* __restrict__ bcur,
                             int* __restrict__ offs, int N, int ET) {
    extern __shared__ int sm[];
    for (int i = threadIdx.x; i < NB; i += blockDim.x) sm[i] = bcnt[i];
    __syncthreads();
    if (threadIdx.x == 0) {
        int run = 0;
        for (int i = 0; i < NB; i++) { int c = sm[i]; sm[i] = run; run += c; }
    }
    __syncthreads();
    for (int i = threadIdx.x; i < NB; i += blockDim.x) { boff[i] = sm[i]; bcur[i] = sm[i]; }
    if (threadIdx.x == 0) { boff[NB] = ET; offs[N] = ET; }
}

__global__ __launch_bounds__(256) void k_bscatter(const int* __restrict__ ei, int E, int ET, int NB,
                                                  int* __restrict__ bcur,
                                                  long long* __restrict__ tmp) {
    extern __shared__ int sm2[];
    int* hist = sm2;
    int* cur = sm2 + NB;
    const int CH = 4096;
    int c0 = blockIdx.x * CH;
    int c1 = min(ET, c0 + CH);
    for (int i = threadIdx.x; i < NB; i += 256) hist[i] = 0;
    __syncthreads();
    for (int i = c0 + threadIdx.x; i < c1; i += 256) {
        int d = (i < E) ? ei[E + i] : (i - E);
        atomicAdd(&hist[d >> BBITS], 1);
    }
    __syncthreads();
    for (int i = threadIdx.x; i < NB; i += 256) {
        int c = hist[i];
        cur[i] = c ? atomicAdd(&bcur[i], c) : 0;
    }
    __syncthreads();
    for (int i = c0 + threadIdx.x; i < c1; i += 256) {
        int s = (i < E) ? ei[i] : (i - E);
        int d = (i < E) ? ei[E + i] : (i - E);
        int pos = atomicAdd(&cur[d >> BBITS], 1);
        tmp[pos] = ((long long)d << 32) | (unsigned)s;
    }
}

__global__ __launch_bounds__(256) void k_csrfin(const long long* __restrict__ tmp,
                                                const int* __restrict__ boff, int NB, int N,
                                                int* __restrict__ offs, int* __restrict__ ssrc) {
    __shared__ int deg[BSZ], cur[BSZ], sc[BSZ];
    int b = blockIdx.x;
    int node0 = b << BBITS;
    int nn = min(BSZ, N - node0);
    int r0 = boff[b], r1 = boff[b + 1];
    int t = threadIdx.x;
    if (t < BSZ) deg[t] = 0;
    __syncthreads();
    for (int i = r0 + t; i < r1; i += 256) {
        int d = (int)(tmp[i] >> 32);
        atomicAdd(&deg[d - node0], 1);
    }
    __syncthreads();
    if (t < BSZ) sc[t] = deg[t];
    __syncthreads();
    for (int o = 1; o < BSZ; o <<= 1) {
        int v = 0;
        if (t < BSZ && t >= o) v = sc[t - o];
        __syncthreads();
        if (t < BSZ) sc[t] += v;
        __syncthreads();
    }
    if (t < BSZ) {
        int ex = sc[t] - deg[t];
        cur[t] = r0 + ex;
        if (t < nn) offs[node0 + t] = r0 + ex;
    }
    __syncthreads();
    for (int i = r0 + t; i < r1; i += 256) {
        long long v = tmp[i];
        int d = (int)(v >> 32);
        int s = (int)(v & 0xffffffffLL);
        int pos = atomicAdd(&cur[d - node0], 1);
        ssrc[pos] = s;
    }
}

// ========== transpose weights to bf16: Wt[n][k] = bf16(W[k][n]) ==========
__global__ __launch_bounds__(256) void k_wt(const float* __restrict__ W, ushort_t* __restrict__ Wt,
                                            int K, int M) {
    for (int idx = blockIdx.x * 256 + threadIdx.x; idx < K * M; idx += gridDim.x * 256) {
        int k = idx / M, n = idx % M;
        Wt[n * K + k] = f2bfbits(W[idx]);
    }
}

// ===== MFMA GEMM + fused alpha: h[N,M](bf16) = x[N,128] @ W[128,M]; as/ad = h·a_* =====
template <int M, int H>
__global__ __launch_bounds__(256) void k_gemm_mfma(const float* __restrict__ x,
                                                   const ushort_t* __restrict__ Wt,
                                                   const float* __restrict__ a_src,
                                                   const float* __restrict__ a_dst,
                                                   ushort_t* __restrict__ h,
                                                   float* __restrict__ as, float* __restrict__ ad,
                                                   int N) {
    constexpr int T = M / 16;  // col tiles
    int t = threadIdx.x;
    int w = t >> 6;
    int lane = t & 63;
    int ln = lane & 15;
    int q = lane >> 4;
    int rowA = blockIdx.x * 64 + w * 16 + ln;      // row this lane supplies to A
    int rowD0 = blockIdx.x * 64 + w * 16 + q * 4;  // first D row for this lane

    f32x4 acc[T];
#pragma unroll
    for (int i = 0; i < T; i++) acc[i] = (f32x4){0.f, 0.f, 0.f, 0.f};

#pragma unroll
    for (int kc = 0; kc < 4; kc++) {
        bf16x8 afrag;
        float xv[8];
        if (rowA < N) {
            float4 v0 = *(const float4*)(x + (size_t)rowA * 128 + kc * 32 + q * 8);
            float4 v1 = *(const float4*)(x + (size_t)rowA * 128 + kc * 32 + q * 8 + 4);
            xv[0] = v0.x; xv[1] = v0.y; xv[2] = v0.z; xv[3] = v0.w;
            xv[4] = v1.x; xv[5] = v1.y; xv[6] = v1.z; xv[7] = v1.w;
        } else {
#pragma unroll
            for (int j = 0; j < 8; j++) xv[j] = 0.f;
        }
#pragma unroll
        for (int j = 0; j < 8; j++) afrag[j] = (short)f2bfbits(xv[j]);
#pragma unroll
        for (int tt = 0; tt < T; tt++) {
            bf16x8 bfrag = *(const bf16x8*)(Wt + (size_t)(tt * 16 + ln) * 128 + kc * 32 + q * 8);
            acc[tt] = __builtin_amdgcn_mfma_f32_16x16x32_bf16(afrag, bfrag, acc[tt], 0, 0, 0);
        }
    }

#pragma unroll
    for (int tt = 0; tt < T; tt++)
#pragma unroll
        for (int r = 0; r < 4; r++) {
            int row = rowD0 + r;
            if (row < N) h[(size_t)row * M + tt * 16 + ln] = f2bfbits(acc[tt][r]);
        }

    float avs[T], avd[T];
#pragma unroll
    for (int tt = 0; tt < T; tt++) {
        avs[tt] = a_src[tt * 16 + ln];
        avd[tt] = a_dst[tt * 16 + ln];
    }
#pragma unroll
    for (int r = 0; r < 4; r++) {
        int row = rowD0 + r;
        if (H == 2) {
            float ps0 = 0.f, ps1 = 0.f, pd0 = 0.f, pd1 = 0.f;
#pragma unroll
            for (int tt = 0; tt < T / 2; tt++) { ps0 += acc[tt][r] * avs[tt]; pd0 += acc[tt][r] * avd[tt]; }
#pragma unroll
            for (int tt = T / 2; tt < T; tt++) { ps1 += acc[tt][r] * avs[tt]; pd1 += acc[tt][r] * avd[tt]; }
#pragma unroll
            for (int o = 8; o; o >>= 1) {
                ps0 += __shfl_down(ps0, o, 16); pd0 += __shfl_down(pd0, o, 16);
                ps1 += __shfl_down(ps1, o, 16); pd1 += __shfl_down(pd1, o, 16);
            }
            if (ln == 0 && row < N) {
                as[(size_t)row * 2] = ps0; as[(size_t)row * 2 + 1] = ps1;
                ad[(size_t)row * 2] = pd0; ad[(size_t)row * 2 + 1] = pd1;
            }
        } else {
            float ps = 0.f, pd = 0.f;
#pragma unroll
            for (int tt = 0; tt < T; tt++) { ps += acc[tt][r] * avs[tt]; pd += acc[tt][r] * avd[tt]; }
#pragma unroll
            for (int o = 8; o; o >>= 1) {
                ps += __shfl_down(ps, o, 16); pd += __shfl_down(pd, o, 16);
            }
            if (ln == 0 && row < N) { as[row] = ps; ad[row] = pd; }
        }
    }
}

// ======= fused softmax + aggregation: 8 B/lane rows, LDS {so,p} meta, mask-free =======
// G = 16*H lanes cover one row (uint2/lane); EPW = 64/G edges per group-load.
// Meta per (edge, head) = {byte_offset, p} uint2 in per-wave LDS; pad lanes store
// {0, 0} so the gather loop runs UNMASKED (pad slots read row 0 with p=0).
// Slot index <= 63 provably for ne <= 64, so no &63 / cmp / cndmask at all.
template <int H, bool ELU_ACT>
__global__ __launch_bounds__(256) void k_agg_fused(const int* __restrict__ offs,
                                                   const int* __restrict__ ssrc,
                                                   const ushort_t* __restrict__ h,
                                                   const float* __restrict__ as,
                                                   const float* __restrict__ ad,
                                                   const float* __restrict__ bias,
                                                   float* __restrict__ z, int N) {
    constexpr int G = 16 * H;    // lanes per source row (8 B each)
    constexpr int EPW = 64 / G;  // edges per group-load
    constexpr int RB = H * 128;  // row bytes (bf16)
    __shared__ uint2 meta[4][64 * H];
    int wv = threadIdx.x >> 6;
    int lane = threadIdx.x & 63;
    int d = (blockIdx.x * 256 + threadIdx.x) >> 6;
    if (d >= N) return;
    uint2* mw = meta[wv];
    int cpos = lane % G;  // uint2 chunk index within row (channels cpos*4..+3)
    int sub = lane / G;   // which edge of the group
    int hself = (H == 2) ? (cpos >> 4) : 0;
    const char* hb = (const char*)h;
    int cpo8 = cpos * 8;
    // meta read base: H=2 offset = el*16 + hself*8 (el = g*2+sub) -> g*32 + sub*16 + hself*8
    //                 H=1 offset = el*8          (el = g*4+sub) -> g*32 + sub*8
    const char* mbase = (const char*)mw + ((H == 2) ? (sub * 16 + hself * 8) : (sub * 8));

    float adh[H], den[H];
#pragma unroll
    for (int hh = 0; hh < H; hh++) { adh[hh] = ad[(size_t)d * H + hh]; den[hh] = 0.f; }
    v2f acc2[2];
    acc2[0] = (v2f){0.f, 0.f};
    acc2[1] = (v2f){0.f, 0.f};

    int e0 = offs[d], e1 = offs[d + 1];
    for (int cb = e0; cb < e1; cb += 64) {
        int ne = min(64, e1 - cb);
        unsigned so = 0;
        float p[H];
#pragma unroll
        for (int hh = 0; hh < H; hh++) p[hh] = 0.f;
        if (lane < ne) {
            int s_l = ssrc[cb + lane];
            so = (unsigned)s_l * RB;  // pre-scaled 32-bit byte offset
            if (H == 2) {
                float2 av = ((const float2*)as)[s_l];
                p[0] = __expf(LRELU(av.x + adh[0]));
                p[1] = __expf(LRELU(av.y + adh[1]));
            } else {
                p[0] = __expf(LRELU(as[s_l] + adh[0]));
            }
        }
#pragma unroll
        for (int hh = 0; hh < H; hh++) den[hh] += wsum(p[hh]);
        if (H == 2) {
            ((uint4*)mw)[lane] =
                make_uint4(so, __float_as_uint(p[0]), so, __float_as_uint(p[1]));
        } else {
            mw[lane] = make_uint2(so, __float_as_uint(p[0]));
        }
        // unmasked gather: 4 groups per iteration, meta via single ds_read_b64 each
        int ng = (ne + EPW - 1) / EPW;
        for (int g0 = 0; g0 < ng; g0 += 4) {
            uint2 m[4];
#pragma unroll
            for (int g = 0; g < 4; g++) m[g] = *(const uint2*)(mbase + (g0 + g) * 32);
            uint2 hv[4];
#pragma unroll
            for (int g = 0; g < 4; g++) hv[g] = *(const uint2*)(hb + (m[g].x + cpo8));
#pragma unroll
            for (int g = 0; g < 4; g++) {
                float pvs = __uint_as_float(m[g].y);
                v2f pv = {pvs, pvs};
                v2f t0 = {__uint_as_float(hv[g].x << 16), __uint_as_float(hv[g].x & 0xffff0000u)};
                v2f t1 = {__uint_as_float(hv[g].y << 16), __uint_as_float(hv[g].y & 0xffff0000u)};
                acc2[0] += pv * t0;
                acc2[1] += pv * t1;
            }
        }
    }
    // fold sub-wave partials: lanes sharing cpos sum across sub
#pragma unroll
    for (int o = G; o < 64; o <<= 1) {
        acc2[0][0] += __shfl_xor(acc2[0][0], o);
        acc2[0][1] += __shfl_xor(acc2[0][1], o);
        acc2[1][0] += __shfl_xor(acc2[1][0], o);
        acc2[1][1] += __shfl_xor(acc2[1][1], o);
    }
    if (lane < G) {
        float inv = 1.f / ((H == 2 && hself) ? den[1] : den[0]);
        float vout[4];
        vout[0] = acc2[0][0] * inv + bias[cpos * 4 + 0];
        vout[1] = acc2[0][1] * inv + bias[cpos * 4 + 1];
        vout[2] = acc2[1][0] * inv + bias[cpos * 4 + 2];
        vout[3] = acc2[1][1] * inv + bias[cpos * 4 + 3];
        if (ELU_ACT) {
#pragma unroll
            for (int i = 0; i < 4; i++) vout[i] = vout[i] > 0.f ? vout[i] : expm1f(vout[i]);
        }
        *(float4*)(z + (size_t)d * (H * 64) + cpos * 4) =
            make_float4(vout[0], vout[1], vout[2], vout[3]);
    }
}

// =================== decode: 2 pairs per wave, float2 per lane ===================
__global__ __launch_bounds__(256) void k_decode(const int* __restrict__ eli,
                                                const float* __restrict__ z,
                                                float* __restrict__ out, int EL) {
    int wid = (blockIdx.x * 256 + threadIdx.x) >> 6;
    int lane = threadIdx.x & 63;
    int pi = wid * 2 + (lane >> 5);
    if (pi >= EL) return;
    int hl = lane & 31;
    int a = eli[pi], b = eli[EL + pi];
    float2 za = ((const float2*)(z + (size_t)a * 64))[hl];
    float2 zb = ((const float2*)(z + (size_t)b * 64))[hl];
    float p = za.x * zb.x + za.y * zb.y;
#pragma unroll
    for (int o = 16; o; o >>= 1) p += __shfl_down(p, o, 32);
    if (hl == 0) out[pi] = p;
}

extern "C" void kernel_launch(void* const* d_in, const int* in_sizes, int n_in,
                              void* d_out, int out_size, void* d_ws, size_t ws_size,
                              hipStream_t stream) {
    const float* x   = (const float*)d_in[0];
    const int*   ei  = (const int*)d_in[1];
    const int*   eli = (const int*)d_in[2];
    const float* W1  = (const float*)d_in[3];
    const float* as1 = (const float*)d_in[4];
    const float* ad1 = (const float*)d_in[5];
    const float* b1  = (const float*)d_in[6];
    const float* W2  = (const float*)d_in[7];
    const float* as2 = (const float*)d_in[8];
    const float* ad2 = (const float*)d_in[9];
    const float* b2  = (const float*)d_in[10];

    int N  = in_sizes[0] / 128;
    int E  = in_sizes[1] / 2;
    int EL = in_sizes[2] / 2;
    int ET = E + N;
    int NB = cdiv(N, BSZ);

    char* ws = (char*)d_ws;
    size_t off = 0;
    auto alloc = [&](size_t nbytes) -> void* {
        void* p = ws + off;
        off += (nbytes + 255) & ~(size_t)255;
        return p;
    };
    ushort_t* Hbuf = (ushort_t*)alloc((size_t)N * 128 * 2);  // h1 then h2 (bf16)
    float*    Zbuf = (float*)alloc((size_t)N * 128 * 4);     // z1 then z2 (TMP aliases this)
    float*    AS   = (float*)alloc((size_t)N * 2 * 4);
    float*    AD   = (float*)alloc((size_t)N * 2 * 4);
    int*      OFF  = (int*)alloc((size_t)(N + 1) * 4);
    int*      SSRC = (int*)alloc((size_t)ET * 4);
    int*      BCNT = (int*)alloc((size_t)NB * 4);
    int*      BOFF = (int*)alloc((size_t)(NB + 1) * 4);
    int*      BCUR = (int*)alloc((size_t)NB * 4);
    ushort_t* WT1  = (ushort_t*)alloc(128 * 128 * 2);
    ushort_t* WT2  = (ushort_t*)alloc(64 * 128 * 2);
    long long* TMP = (long long*)Zbuf;  // (d,s) pairs; Zbuf unused until k_agg L1

    // ---- CSR build via bucket sort (shared by both layers) ----
    k_zero_int<<<cdiv(NB, 256), 256, 0, stream>>>(BCNT, NB);
    k_bhist<<<256, 256, NB * 4, stream>>>(ei, E, ET, NB, BCNT);
    k_scan_small<<<1, 256, NB * 4, stream>>>(BCNT, NB, BOFF, BCUR, OFF, N, ET);
    k_bscatter<<<cdiv(ET, 4096), 256, 2 * NB * 4, stream>>>(ei, E, ET, NB, BCUR, TMP);
    k_csrfin<<<NB, 256, 0, stream>>>(TMP, BOFF, NB, N, OFF, SSRC);

    // ---- weight transposes (bf16) ----
    k_wt<<<32, 256, 0, stream>>>(W1, WT1, 128, 128);
    k_wt<<<16, 256, 0, stream>>>(W2, WT2, 128, 64);

    // ---- layer 1: heads=2, C=64, ELU ----
    k_gemm_mfma<128, 2><<<cdiv(N, 64), 256, 0, stream>>>(x, WT1, as1, ad1, Hbuf, AS, AD, N);
    k_agg_fused<2, true><<<cdiv(N, 4), 256, 0, stream>>>(OFF, SSRC, Hbuf, AS, AD, b1, Zbuf, N);

    // ---- layer 2: heads=1, C=64, no activation ----
    k_gemm_mfma<64, 1><<<cdiv(N, 64), 256, 0, stream>>>(Zbuf, WT2, as2, ad2, Hbuf, AS, AD, N);
    k_agg_fused<1, false><<<cdiv(N, 4), 256, 0, stream>>>(OFF, SSRC, Hbuf, AS, AD, b2, Zbuf, N);

    // ---- decode ----
    k_decode<<<cdiv(EL, 8), 256, 0, stream>>>(eli, Zbuf, (float*)d_out, EL);
}